// Round 10
// baseline (163.705 us; speedup 1.0000x reference)
//
#include <hip/hip_runtime.h>

// Problem: B=4, S=1024, D=512, H=8, DH=64. All fp32 in/out.
// Strategy: attn is LINEAR in dots => out = c1*Q(K^T V) + cw*Qhat(Khat^T V) + rank-1 terms.
// Never materialize SxS. bf16 MFMA for ALL GEMM-shaped work.
// 4 launches: k1 (LN+W-transpose), gemm_qkv (input GEMM + fused stats/layout),
// k45_ktv (full-K K^TV + B2 build + R = B2@Wout_h fused), k6_out (block-diag GEMM + bias).

#define R_TOT 4096      // B*S
#define DD 512
#define HB_N 32         // H*B

typedef __attribute__((ext_vector_type(8))) short short8;
typedef __attribute__((ext_vector_type(4))) float f32x4;

static __device__ inline unsigned short f2bf(float f) {
    union { float f; unsigned u; } x{f};
    unsigned r = x.u + 0x7fff + ((x.u >> 16) & 1);
    return (unsigned short)(r >> 16);
}

// scale two packed bf16 (lo,hi) by a,b -> packed bf16
static __device__ inline unsigned scale2(unsigned u, float a, float b) {
    float lo = __uint_as_float(u << 16);
    float hi = __uint_as_float(u & 0xffff0000u);
    return (unsigned)f2bf(lo * a) | ((unsigned)f2bf(hi * b) << 16);
}

// async global->LDS, 16B per lane; LDS dest = wave-uniform base + lane*16
static __device__ inline void async_cp16(const unsigned short* g, unsigned short* l) {
    __builtin_amdgcn_global_load_lds(
        (const __attribute__((address_space(1))) unsigned int*)g,
        (__attribute__((address_space(3))) unsigned int*)l, 16, 0, 0);
}

// ---------------- K1: layernorm->bf16 (1 wave = 1 row, no LDS/barriers);
//                  transpose-cast W_in, W_out -------------------------------------
__global__ __launch_bounds__(256) void k1_ln_prep(
    const float* __restrict__ q, const float* __restrict__ k, const float* __restrict__ v,
    const float* __restrict__ ln_g, const float* __restrict__ ln_b,
    const float* __restrict__ Win, const float* __restrict__ Wout,
    unsigned short* __restrict__ xn, unsigned short* __restrict__ WinT,
    unsigned short* __restrict__ WoutT)
{
    int blk = blockIdx.x;
    int t = threadIdx.x, lane = t & 63, wv = t >> 6;
    if (blk < 3072) {
        int row = blk * 4 + wv;                       // 12288 rows total
        const float* src = (row < R_TOT) ? q : (row < 2 * R_TOT ? k : v);
        const float* x = src + (size_t)(row & (R_TOT - 1)) * DD + lane * 8;
        float4 v0 = *(const float4*)x;
        float4 v1 = *(const float4*)(x + 4);
        float s  = v0.x + v0.y + v0.z + v0.w + v1.x + v1.y + v1.z + v1.w;
        float s2 = v0.x * v0.x + v0.y * v0.y + v0.z * v0.z + v0.w * v0.w
                 + v1.x * v1.x + v1.y * v1.y + v1.z * v1.z + v1.w * v1.w;
        #pragma unroll
        for (int o = 32; o; o >>= 1) { s += __shfl_xor(s, o); s2 += __shfl_xor(s2, o); }
        float mu = s * (1.f / 512.f);
        float var = s2 * (1.f / 512.f) - mu * mu;
        float rstd = rsqrtf(var + 1e-5f);
        float4 g0 = *(const float4*)(ln_g + lane * 8);
        float4 g1 = *(const float4*)(ln_g + lane * 8 + 4);
        float4 b0 = *(const float4*)(ln_b + lane * 8);
        float4 b1 = *(const float4*)(ln_b + lane * 8 + 4);
        float e0 = (v0.x - mu) * rstd * g0.x + b0.x;
        float e1 = (v0.y - mu) * rstd * g0.y + b0.y;
        float e2 = (v0.z - mu) * rstd * g0.z + b0.z;
        float e3 = (v0.w - mu) * rstd * g0.w + b0.w;
        float e4 = (v1.x - mu) * rstd * g1.x + b1.x;
        float e5 = (v1.y - mu) * rstd * g1.y + b1.y;
        float e6 = (v1.z - mu) * rstd * g1.z + b1.z;
        float e7 = (v1.w - mu) * rstd * g1.w + b1.w;
        uint4 o;
        o.x = (unsigned)f2bf(e0) | ((unsigned)f2bf(e1) << 16);
        o.y = (unsigned)f2bf(e2) | ((unsigned)f2bf(e3) << 16);
        o.z = (unsigned)f2bf(e4) | ((unsigned)f2bf(e5) << 16);
        o.w = (unsigned)f2bf(e6) | ((unsigned)f2bf(e7) << 16);
        *(uint4*)(xn + (size_t)row * DD + lane * 8) = o;
    } else {
        // 128 transpose blocks: 64 for Win (8x8 tiles of 64x64), 64 for Wout
        __shared__ float tl[64][65];
        int bb = blk - 3072;
        const float* src = (bb & 64) ? Wout : Win;
        unsigned short* dst = (bb & 64) ? WoutT : WinT;
        int tile = bb & 63;
        int r0 = (tile >> 3) * 64, c0 = (tile & 7) * 64;
        #pragma unroll
        for (int rep = 0; rep < 16; rep++) {
            int rr = rep * 4 + (t >> 6), cc = t & 63;
            tl[rr][cc] = src[(size_t)(r0 + rr) * DD + c0 + cc];
        }
        __syncthreads();
        #pragma unroll
        for (int rep = 0; rep < 16; rep++) {
            int rr = rep * 4 + (t >> 6), cc = t & 63;
            dst[(size_t)(c0 + rr) * DD + r0 + cc] = f2bf(tl[cc][rr]);
        }
    }
}

// ---------------- gemm_qkv: xn@Win with fused stats + A2/Kt/Vt epilogue ----------
// grid (4, 96). Block tile 128x128, wave tile 64x64 = one full head width.
// Main loop: BK=64, global_load_lds(16B), XOR-swizzled unpadded LDS.
__global__ __launch_bounds__(256) void gemm_qkv(
    const unsigned short* __restrict__ A, const unsigned short* __restrict__ Bt,
    unsigned short* __restrict__ A2, unsigned short* __restrict__ Kt,
    unsigned short* __restrict__ Vt, float* __restrict__ kinv,
    float* __restrict__ kvar, float* __restrict__ kmu)
{
    __shared__ __align__(16) char smbuf[39936];
    unsigned short* AsF = (unsigned short*)smbuf;              // [128][64] unpadded
    unsigned short* BsF = (unsigned short*)(smbuf + 16384);    // [128][64] unpadded
    int t = threadIdx.x, lane = t & 63, wv = t >> 6;
    int quad = lane >> 4, l15 = lane & 15;
    int m0 = blockIdx.y * 128, n0 = blockIdx.x * 128;
    int wr = (wv >> 1) * 64, wc = (wv & 1) * 64;
    int swz = l15 & 7;                       // frag-read swizzle (row&7 == l15&7)
    int r8 = lane >> 3, cc8 = lane & 7;      // staging: lane -> (row-in-group, chunk')
    f32x4 acc[4][4] = {};
    for (int kt = 0; kt < 512; kt += 64) {
        __syncthreads();
        #pragma unroll
        for (int gi = 0; gi < 4; gi++) {
            int grp = wv * 4 + gi;           // 16 groups of 8 rows each, per side
            int row = grp * 8 + r8;
            int col = kt + ((cc8 ^ (row & 7)) << 3);
            async_cp16(A + (size_t)(m0 + row) * 512 + col, AsF + grp * 512);
            async_cp16(Bt + (size_t)(n0 + row) * 512 + col, BsF + grp * 512);
        }
        __syncthreads();
        #pragma unroll
        for (int kk = 0; kk < 2; kk++) {
            short8 af[4], bf[4];
            int ksl = ((kk * 4 + quad) ^ swz) << 3;
            #pragma unroll
            for (int i = 0; i < 4; i++) af[i] = *(const short8*)&AsF[(wr + i * 16 + l15) * 64 + ksl];
            #pragma unroll
            for (int j = 0; j < 4; j++) bf[j] = *(const short8*)&BsF[(wc + j * 16 + l15) * 64 + ksl];
            #pragma unroll
            for (int i = 0; i < 4; i++)
                #pragma unroll
                for (int j = 0; j < 4; j++)
                    acc[i][j] = __builtin_amdgcn_mfma_f32_16x16x32_bf16(af[i], bf[j], acc[i][j], 0, 0, 0);
        }
    }
    __syncthreads();   // protect LDS reuse (other waves may still be reading As/Bs)

    unsigned short* tile = (unsigned short*)(smbuf + wv * 9216);          // [64][72]
    float* st     = (float*)(smbuf + 36864 + wv * 768);
    float* st_inv = st;
    float* st_var = st + 64;
    float* st_mu  = st + 128;

    int typ  = m0 >> 12;                 // 0=q, 1=k, 2=v
    int rloc = (m0 & 4095) + wr;         // row-in-type of wave's first row
    int b = rloc >> 10, sb = rloc & 1023;
    int h = (n0 + wc) >> 6;
    int hb = h * 4 + b;

    if (typ < 2) {
        #pragma unroll
        for (int i = 0; i < 4; i++)
            #pragma unroll
            for (int r = 0; r < 4; r++) {
                float a0 = acc[i][0][r], a1 = acc[i][1][r], a2 = acc[i][2][r], a3 = acc[i][3][r];
                float s1 = a0 + a1 + a2 + a3;
                float s2 = a0 * a0 + a1 * a1 + a2 * a2 + a3 * a3;
                #pragma unroll
                for (int o = 1; o < 16; o <<= 1) { s1 += __shfl_xor(s1, o); s2 += __shfl_xor(s2, o); }
                if (l15 == 0) {
                    int sl = i * 16 + quad * 4 + r;
                    float mu = s1 * (1.f / 64.f);
                    st_inv[sl] = rsqrtf(fmaxf(s2, 1e-20f));      // 1/||f||; +1e-8 on qn*kn negligible
                    st_var[sl] = (s2 - 64.f * mu * mu) * (1.f / 63.f);  // ddof=1
                    st_mu[sl]  = mu;
                }
            }
    }
    // stage values into per-wave LDS tile: q -> [s][d]; k,v -> [d][s]
    #pragma unroll
    for (int i = 0; i < 4; i++)
        #pragma unroll
        for (int j = 0; j < 4; j++)
            #pragma unroll
            for (int r = 0; r < 4; r++) {
                int sl = i * 16 + quad * 4 + r, d = j * 16 + l15;
                unsigned short bv = f2bf(acc[i][j][r]);
                tile[(typ == 0) ? (sl * 72 + d) : (d * 72 + sl)] = bv;
            }
    // same-wave LDS producer/consumer: compiler inserts lgkmcnt waits

    if (typ == 0) {
        // A2[hb][s][160] = [ q | qhat | var, mu | zeros ]
        unsigned short* ob = A2 + ((size_t)hb * 1024 + sb) * 160;
        #pragma unroll
        for (int it = 0; it < 8; it++) {
            int sl = it * 8 + (lane >> 3), ch = (lane & 7) * 8;
            uint4 raw = *(uint4*)&tile[sl * 72 + ch];
            *(uint4*)(ob + (size_t)sl * 160 + ch) = raw;
            float iv = st_inv[sl];
            uint4 o2;
            o2.x = scale2(raw.x, iv, iv); o2.y = scale2(raw.y, iv, iv);
            o2.z = scale2(raw.z, iv, iv); o2.w = scale2(raw.w, iv, iv);
            *(uint4*)(ob + (size_t)sl * 160 + 64 + ch) = o2;
        }
        {
            int sl = lane;
            uint4 z = {0, 0, 0, 0};
            uint4 t0 = z;
            t0.x = (unsigned)f2bf(st_var[sl]) | ((unsigned)f2bf(st_mu[sl]) << 16);
            unsigned short* p = ob + (size_t)sl * 160 + 128;
            *(uint4*)p = t0;
            *(uint4*)(p + 8) = z; *(uint4*)(p + 16) = z; *(uint4*)(p + 24) = z;
        }
    } else if (typ == 1) {
        // Kt[hb][64][m] raw k (khat applied later in k45 from kinv); stats fp32.
        unsigned short* kb = Kt + (size_t)hb * 64 * 1024 + sb;
        #pragma unroll
        for (int it = 0; it < 8; it++) {
            int d = it * 8 + (lane >> 3), ch = (lane & 7) * 8;
            uint4 raw = *(uint4*)&tile[d * 72 + ch];
            *(uint4*)(kb + (size_t)d * 1024 + ch) = raw;
        }
        int mi = hb * 1024 + sb + lane;
        kinv[mi] = st_inv[lane];
        kvar[mi] = st_var[lane];
        kmu[mi]  = st_mu[lane];
    } else {
        unsigned short* vb = Vt + (size_t)hb * 64 * 1024 + sb;
        #pragma unroll
        for (int it = 0; it < 8; it++) {
            int d = it * 8 + (lane >> 3), ch = (lane & 7) * 8;
            uint4 raw = *(uint4*)&tile[d * 72 + ch];
            *(uint4*)(vb + (size_t)d * 1024 + ch) = raw;
        }
    }
}

// ---------------- K45: per hb full-K: B2 = scale(L^T V); R = B2 @ Wout_h ----------
// L rows: [k | k*inv | var | mu | (zeros)]; built in LDS from Kt + stats.
// grid 32, block 256 (4 waves; wave w owns n-cols w*16..+15, 9 m-tiles = 144 rows).
// Epilogue: R[hb][nt][n64][k160] bf16 = B2 @ WoutT-head-slab (fused 2nd GEMM).
__global__ __launch_bounds__(256) void k45_ktv(
    const unsigned short* __restrict__ Kt, const unsigned short* __restrict__ Vt,
    const float* __restrict__ kinv, const float* __restrict__ kvar,
    const float* __restrict__ kmu, const unsigned short* __restrict__ WoutT,
    unsigned short* __restrict__ Rbuf,
    const float* __restrict__ covp, const float* __restrict__ varp)
{
    __shared__ __align__(16) unsigned short As[144][136];
    __shared__ __align__(16) unsigned short Bs[64][136];
    __shared__ float sinv[128], svar[128], smu[128];
    int hb = blockIdx.x;
    int t = threadIdx.x, lane = t & 63, wv = t >> 6;
    int quad = lane >> 4, l15 = lane & 15;
    float cov = covp[0], vw = varp[0];
    float c1 = cov * (1.f / 64.f), cw = 1.f - cov - vw;
    float vw64 = vw * (1.f / 64.f), c2 = -cov;
    const unsigned short* Kb = Kt + (size_t)hb * 64 * 1024;
    const unsigned short* Vb = Vt + (size_t)hb * 64 * 1024;
    int sbase = hb * 1024;
    // zero rows 130-143 (cols 0-127) once so their C-rows stay finite (0)
    if (t < 224) {
        int row = 130 + (t >> 4), co = (t & 15) * 8;
        uint4 z = {0, 0, 0, 0};
        *(uint4*)&As[row][co] = z;
    }
    f32x4 acc[9] = {};
    for (int kc = 0; kc < 8; kc++) {
        __syncthreads();
        if (t < 128) {
            int m = kc * 128 + t;
            sinv[t] = kinv[sbase + m]; svar[t] = kvar[sbase + m]; smu[t] = kmu[sbase + m];
        }
        uint4 kraw[4];
        #pragma unroll
        for (int i = 0; i < 4; i++) {
            int id = i * 256 + t, row = id >> 4, co = (id & 15) * 8;
            kraw[i] = *(const uint4*)(Kb + (size_t)row * 1024 + kc * 128 + co);
            *(uint4*)&As[row][co] = kraw[i];
            uint4 vr = *(const uint4*)(Vb + (size_t)row * 1024 + kc * 128 + co);
            *(uint4*)&Bs[row][co] = vr;
        }
        __syncthreads();
        #pragma unroll
        for (int i = 0; i < 4; i++) {
            int id = i * 256 + t, row = id >> 4, co = (id & 15) * 8;
            float4 iva = *(const float4*)&sinv[co];
            float4 ivb = *(const float4*)&sinv[co + 4];
            uint4 o;
            o.x = scale2(kraw[i].x, iva.x, iva.y); o.y = scale2(kraw[i].y, iva.z, iva.w);
            o.z = scale2(kraw[i].z, ivb.x, ivb.y); o.w = scale2(kraw[i].w, ivb.z, ivb.w);
            *(uint4*)&As[64 + row][co] = o;
        }
        if (t < 32) {
            int which = t >> 4, j0 = (t & 15) * 8;
            const float* sp = (which ? smu : svar) + j0;
            uint4 o;
            o.x = (unsigned)f2bf(sp[0]) | ((unsigned)f2bf(sp[1]) << 16);
            o.y = (unsigned)f2bf(sp[2]) | ((unsigned)f2bf(sp[3]) << 16);
            o.z = (unsigned)f2bf(sp[4]) | ((unsigned)f2bf(sp[5]) << 16);
            o.w = (unsigned)f2bf(sp[6]) | ((unsigned)f2bf(sp[7]) << 16);
            *(uint4*)&As[128 + which][j0] = o;
        }
        __syncthreads();
        #pragma unroll
        for (int kk = 0; kk < 4; kk++) {
            short8 bfrag = *(const short8*)&Bs[wv * 16 + l15][kk * 32 + quad * 8];
            #pragma unroll
            for (int mt = 0; mt < 9; mt++) {
                short8 afrag = *(const short8*)&As[mt * 16 + l15][kk * 32 + quad * 8];
                acc[mt] = __builtin_amdgcn_mfma_f32_16x16x32_bf16(afrag, bfrag, acc[mt], 0, 0, 0);
            }
        }
    }
    // ---- epilogue: Ls[kk][d] = scaled B2 (bf16); then R = Ls @ Wout_h ----
    __syncthreads();
    unsigned short* Ls = (unsigned short*)As;     // [160][72], fits in As region
    {
        int d = wv * 16 + l15;
        #pragma unroll
        for (int mt = 0; mt < 9; mt++)
            #pragma unroll
            for (int r = 0; r < 4; r++) {
                int kk = mt * 16 + quad * 4 + r;
                float scale = (kk < 64) ? c1 : (kk < 128) ? cw : (kk == 128) ? vw64 : (kk == 129) ? c2 : 0.f;
                Ls[kk * 72 + d] = f2bf(scale * acc[mt][r]);
            }
        #pragma unroll
        for (int r = 0; r < 4; r++)               // rows 144-159 = 0
            Ls[(144 + quad * 4 + r) * 72 + d] = 0;
    }
    __syncthreads();
    int h = hb >> 2;
    unsigned short* Rb = Rbuf + (size_t)hb * 8 * 64 * 160;
    for (int nt = 0; nt < 8; nt++) {
        int n = nt * 64 + wv * 16 + l15;
        f32x4 a2[10] = {};
        #pragma unroll
        for (int kk2 = 0; kk2 < 2; kk2++) {
            short8 bfrag = *(const short8*)(WoutT + (size_t)n * 512 + h * 64 + kk2 * 32 + quad * 8);
            #pragma unroll
            for (int mt = 0; mt < 10; mt++) {
                short8 afrag = *(const short8*)&Ls[(mt * 16 + l15) * 72 + kk2 * 32 + quad * 8];
                a2[mt] = __builtin_amdgcn_mfma_f32_16x16x32_bf16(afrag, bfrag, a2[mt], 0, 0, 0);
            }
        }
        unsigned short* ro = Rb + ((size_t)nt * 64 + wv * 16 + l15) * 160;
        #pragma unroll
        for (int mt = 0; mt < 10; mt++)
            #pragma unroll
            for (int r = 0; r < 4; r++)
                ro[mt * 16 + quad * 4 + r] = f2bf(a2[mt][r]);
    }
}

// ---------------- k6_out: out = block-diag(A2) @ R + bias  (K = 8h x 160) ---------
// grid (8 ntiles of 64, 32 mtiles of 128) = 256 blocks.
__global__ __launch_bounds__(256) void k6_out(
    const unsigned short* __restrict__ A2, const unsigned short* __restrict__ Rbuf,
    float* __restrict__ C, const float* __restrict__ bias)
{
    int m0 = blockIdx.y * 128;           // global out row
    int nt = blockIdx.x;                 // 64-col tile
    int b = m0 >> 10, s0 = m0 & 1023;
    int t = threadIdx.x, lane = t & 63, wv = t >> 6;
    int quad = lane >> 4, l15 = lane & 15;
    __shared__ __align__(16) unsigned short As[128][40];
    __shared__ __align__(16) unsigned short Bs[64][40];
    f32x4 acc[2][4] = {};
    for (int h = 0; h < 8; h++) {
        int hb = h * 4 + b;
        const unsigned short* Ab = A2 + ((size_t)hb * 1024 + s0) * 160;
        const unsigned short* Bb = Rbuf + ((size_t)(hb * 8 + nt)) * 64 * 160;
        for (int kt = 0; kt < 160; kt += 32) {
            __syncthreads();
            #pragma unroll
            for (int ld = 0; ld < 2; ld++) {
                int id = ld * 256 + t;
                int row = id >> 2, co = (id & 3) * 8;
                *(uint4*)&As[row][co] = *(const uint4*)(Ab + (size_t)row * 160 + kt + co);
            }
            {
                int row = t >> 2, co = (t & 3) * 8;
                *(uint4*)&Bs[row][co] = *(const uint4*)(Bb + (size_t)row * 160 + kt + co);
            }
            __syncthreads();
            short8 af[2], bf[4];
            #pragma unroll
            for (int i = 0; i < 2; i++) af[i] = *(const short8*)&As[wv * 32 + i * 16 + l15][quad * 8];
            #pragma unroll
            for (int j = 0; j < 4; j++) bf[j] = *(const short8*)&Bs[j * 16 + l15][quad * 8];
            #pragma unroll
            for (int i = 0; i < 2; i++)
                #pragma unroll
                for (int j = 0; j < 4; j++)
                    acc[i][j] = __builtin_amdgcn_mfma_f32_16x16x32_bf16(af[i], bf[j], acc[i][j], 0, 0, 0);
        }
    }
    #pragma unroll
    for (int i = 0; i < 2; i++)
        #pragma unroll
        for (int j = 0; j < 4; j++)
            #pragma unroll
            for (int r = 0; r < 4; r++) {
                int rr = m0 + wv * 32 + i * 16 + quad * 4 + r;
                int cc = nt * 64 + j * 16 + l15;
                C[(size_t)rr * 512 + cc] = acc[i][j][r] + bias[cc];
            }
}

extern "C" void kernel_launch(void* const* d_in, const int* in_sizes, int n_in,
                              void* d_out, int out_size, void* d_ws, size_t ws_size,
                              hipStream_t stream)
{
    const float* q    = (const float*)d_in[0];
    const float* k    = (const float*)d_in[1];
    const float* v    = (const float*)d_in[2];
    const float* ln_g = (const float*)d_in[3];
    const float* ln_b = (const float*)d_in[4];
    const float* Win  = (const float*)d_in[5];
    const float* Wout = (const float*)d_in[6];
    const float* bout = (const float*)d_in[7];
    const float* covw = (const float*)d_in[8];
    const float* varw = (const float*)d_in[9];

    char* ws = (char*)d_ws;
    size_t off = 0;
    auto alloc = [&](size_t bytes) { size_t r = off; off += (bytes + 255) & ~(size_t)255; return r; };
    unsigned short* xn    = (unsigned short*)(ws + alloc((size_t)3 * R_TOT * DD * 2));
    unsigned short* WinT  = (unsigned short*)(ws + alloc((size_t)DD * DD * 2));
    unsigned short* WoutT = (unsigned short*)(ws + alloc((size_t)DD * DD * 2));
    unsigned short* A2    = (unsigned short*)(ws + alloc((size_t)HB_N * 1024 * 160 * 2));
    unsigned short* Kt    = (unsigned short*)(ws + alloc((size_t)HB_N * 64 * 1024 * 2));
    unsigned short* Vt    = (unsigned short*)(ws + alloc((size_t)HB_N * 64 * 1024 * 2));
    float*          kinv  = (float*)(ws + alloc((size_t)HB_N * 1024 * 4));
    float*          kvar  = (float*)(ws + alloc((size_t)HB_N * 1024 * 4));
    float*          kmu   = (float*)(ws + alloc((size_t)HB_N * 1024 * 4));
    unsigned short* Rbuf  = (unsigned short*)(ws + alloc((size_t)HB_N * 8 * 64 * 160 * 2));
    (void)ws_size; (void)in_sizes; (void)n_in; (void)out_size;

    k1_ln_prep<<<3072 + 128, 256, 0, stream>>>(q, k, v, ln_g, ln_b, Win, Wout, xn, WinT, WoutT);
    gemm_qkv<<<dim3(4, 96), 256, 0, stream>>>(xn, WinT, A2, Kt, Vt, kinv, kvar, kmu);
    k45_ktv<<<HB_N, 256, 0, stream>>>(Kt, Vt, kinv, kvar, kmu, WoutT, Rbuf, covw, varw);
    k6_out<<<dim3(8, 32), 256, 0, stream>>>(A2, Rbuf, (float*)d_out, bout);
}

// Round 11
// 148.248 us; speedup vs baseline: 1.1043x; 1.1043x over previous
//
#include <hip/hip_runtime.h>

// Problem: B=4, S=1024, D=512, H=8, DH=64. All fp32 in/out.
// Strategy: attn is LINEAR in dots => out = c1*Q(K^T V) + cw*Qhat(Khat^T V) + rank-1 terms.
// Never materialize SxS. bf16 MFMA for ALL GEMM-shaped work.
// 5 launches: k1 (LN+W-transpose), gemm_qkv (input GEMM + fused stats/layout),
// k45_ktv (full-K K^TV + B2 build), k6_apply, gemm_out.   [R9 best-known config]

#define R_TOT 4096      // B*S
#define DD 512
#define HB_N 32         // H*B

typedef __attribute__((ext_vector_type(8))) short short8;
typedef __attribute__((ext_vector_type(4))) float f32x4;

static __device__ inline unsigned short f2bf(float f) {
    union { float f; unsigned u; } x{f};
    unsigned r = x.u + 0x7fff + ((x.u >> 16) & 1);
    return (unsigned short)(r >> 16);
}

// scale two packed bf16 (lo,hi) by a,b -> packed bf16
static __device__ inline unsigned scale2(unsigned u, float a, float b) {
    float lo = __uint_as_float(u << 16);
    float hi = __uint_as_float(u & 0xffff0000u);
    return (unsigned)f2bf(lo * a) | ((unsigned)f2bf(hi * b) << 16);
}

// async global->LDS, 16B per lane; LDS dest = wave-uniform base + lane*16
static __device__ inline void async_cp16(const unsigned short* g, unsigned short* l) {
    __builtin_amdgcn_global_load_lds(
        (const __attribute__((address_space(1))) unsigned int*)g,
        (__attribute__((address_space(3))) unsigned int*)l, 16, 0, 0);
}

// ---------------- K1: layernorm->bf16 (1 wave = 1 row, no LDS/barriers);
//                  transpose-cast W_in, W_out -------------------------------------
__global__ __launch_bounds__(256) void k1_ln_prep(
    const float* __restrict__ q, const float* __restrict__ k, const float* __restrict__ v,
    const float* __restrict__ ln_g, const float* __restrict__ ln_b,
    const float* __restrict__ Win, const float* __restrict__ Wout,
    unsigned short* __restrict__ xn, unsigned short* __restrict__ WinT,
    unsigned short* __restrict__ WoutT)
{
    int blk = blockIdx.x;
    int t = threadIdx.x, lane = t & 63, wv = t >> 6;
    if (blk < 3072) {
        int row = blk * 4 + wv;                       // 12288 rows total
        const float* src = (row < R_TOT) ? q : (row < 2 * R_TOT ? k : v);
        const float* x = src + (size_t)(row & (R_TOT - 1)) * DD + lane * 8;
        float4 v0 = *(const float4*)x;
        float4 v1 = *(const float4*)(x + 4);
        float s  = v0.x + v0.y + v0.z + v0.w + v1.x + v1.y + v1.z + v1.w;
        float s2 = v0.x * v0.x + v0.y * v0.y + v0.z * v0.z + v0.w * v0.w
                 + v1.x * v1.x + v1.y * v1.y + v1.z * v1.z + v1.w * v1.w;
        #pragma unroll
        for (int o = 32; o; o >>= 1) { s += __shfl_xor(s, o); s2 += __shfl_xor(s2, o); }
        float mu = s * (1.f / 512.f);
        float var = s2 * (1.f / 512.f) - mu * mu;
        float rstd = rsqrtf(var + 1e-5f);
        float4 g0 = *(const float4*)(ln_g + lane * 8);
        float4 g1 = *(const float4*)(ln_g + lane * 8 + 4);
        float4 b0 = *(const float4*)(ln_b + lane * 8);
        float4 b1 = *(const float4*)(ln_b + lane * 8 + 4);
        float e0 = (v0.x - mu) * rstd * g0.x + b0.x;
        float e1 = (v0.y - mu) * rstd * g0.y + b0.y;
        float e2 = (v0.z - mu) * rstd * g0.z + b0.z;
        float e3 = (v0.w - mu) * rstd * g0.w + b0.w;
        float e4 = (v1.x - mu) * rstd * g1.x + b1.x;
        float e5 = (v1.y - mu) * rstd * g1.y + b1.y;
        float e6 = (v1.z - mu) * rstd * g1.z + b1.z;
        float e7 = (v1.w - mu) * rstd * g1.w + b1.w;
        uint4 o;
        o.x = (unsigned)f2bf(e0) | ((unsigned)f2bf(e1) << 16);
        o.y = (unsigned)f2bf(e2) | ((unsigned)f2bf(e3) << 16);
        o.z = (unsigned)f2bf(e4) | ((unsigned)f2bf(e5) << 16);
        o.w = (unsigned)f2bf(e6) | ((unsigned)f2bf(e7) << 16);
        *(uint4*)(xn + (size_t)row * DD + lane * 8) = o;
    } else {
        // 128 transpose blocks: 64 for Win (8x8 tiles of 64x64), 64 for Wout
        __shared__ float tl[64][65];
        int bb = blk - 3072;
        const float* src = (bb & 64) ? Wout : Win;
        unsigned short* dst = (bb & 64) ? WoutT : WinT;
        int tile = bb & 63;
        int r0 = (tile >> 3) * 64, c0 = (tile & 7) * 64;
        #pragma unroll
        for (int rep = 0; rep < 16; rep++) {
            int rr = rep * 4 + (t >> 6), cc = t & 63;
            tl[rr][cc] = src[(size_t)(r0 + rr) * DD + c0 + cc];
        }
        __syncthreads();
        #pragma unroll
        for (int rep = 0; rep < 16; rep++) {
            int rr = rep * 4 + (t >> 6), cc = t & 63;
            dst[(size_t)(c0 + rr) * DD + r0 + cc] = f2bf(tl[cc][rr]);
        }
    }
}

// ---------------- gemm_qkv: xn@Win with fused stats + A2/Kt/Vt epilogue ----------
// grid (4, 96). Block tile 128x128, wave tile 64x64 = one full head width.
// Main loop: BK=64, global_load_lds(16B), XOR-swizzled unpadded LDS.
__global__ __launch_bounds__(256) void gemm_qkv(
    const unsigned short* __restrict__ A, const unsigned short* __restrict__ Bt,
    unsigned short* __restrict__ A2, unsigned short* __restrict__ Kt,
    unsigned short* __restrict__ Vt, float* __restrict__ kinv,
    float* __restrict__ kvar, float* __restrict__ kmu)
{
    __shared__ __align__(16) char smbuf[39936];
    unsigned short* AsF = (unsigned short*)smbuf;              // [128][64] unpadded
    unsigned short* BsF = (unsigned short*)(smbuf + 16384);    // [128][64] unpadded
    int t = threadIdx.x, lane = t & 63, wv = t >> 6;
    int quad = lane >> 4, l15 = lane & 15;
    int m0 = blockIdx.y * 128, n0 = blockIdx.x * 128;
    int wr = (wv >> 1) * 64, wc = (wv & 1) * 64;
    int swz = l15 & 7;                       // frag-read swizzle (row&7 == l15&7)
    int r8 = lane >> 3, cc8 = lane & 7;      // staging: lane -> (row-in-group, chunk')
    f32x4 acc[4][4] = {};
    for (int kt = 0; kt < 512; kt += 64) {
        __syncthreads();
        #pragma unroll
        for (int gi = 0; gi < 4; gi++) {
            int grp = wv * 4 + gi;           // 16 groups of 8 rows each, per side
            int row = grp * 8 + r8;
            int col = kt + ((cc8 ^ (row & 7)) << 3);
            async_cp16(A + (size_t)(m0 + row) * 512 + col, AsF + grp * 512);
            async_cp16(Bt + (size_t)(n0 + row) * 512 + col, BsF + grp * 512);
        }
        __syncthreads();
        #pragma unroll
        for (int kk = 0; kk < 2; kk++) {
            short8 af[4], bf[4];
            int ksl = ((kk * 4 + quad) ^ swz) << 3;
            #pragma unroll
            for (int i = 0; i < 4; i++) af[i] = *(const short8*)&AsF[(wr + i * 16 + l15) * 64 + ksl];
            #pragma unroll
            for (int j = 0; j < 4; j++) bf[j] = *(const short8*)&BsF[(wc + j * 16 + l15) * 64 + ksl];
            #pragma unroll
            for (int i = 0; i < 4; i++)
                #pragma unroll
                for (int j = 0; j < 4; j++)
                    acc[i][j] = __builtin_amdgcn_mfma_f32_16x16x32_bf16(af[i], bf[j], acc[i][j], 0, 0, 0);
        }
    }
    __syncthreads();   // protect LDS reuse (other waves may still be reading As/Bs)

    unsigned short* tile = (unsigned short*)(smbuf + wv * 9216);          // [64][72]
    float* st     = (float*)(smbuf + 36864 + wv * 768);
    float* st_inv = st;
    float* st_var = st + 64;
    float* st_mu  = st + 128;

    int typ  = m0 >> 12;                 // 0=q, 1=k, 2=v
    int rloc = (m0 & 4095) + wr;         // row-in-type of wave's first row
    int b = rloc >> 10, sb = rloc & 1023;
    int h = (n0 + wc) >> 6;
    int hb = h * 4 + b;

    if (typ < 2) {
        #pragma unroll
        for (int i = 0; i < 4; i++)
            #pragma unroll
            for (int r = 0; r < 4; r++) {
                float a0 = acc[i][0][r], a1 = acc[i][1][r], a2 = acc[i][2][r], a3 = acc[i][3][r];
                float s1 = a0 + a1 + a2 + a3;
                float s2 = a0 * a0 + a1 * a1 + a2 * a2 + a3 * a3;
                #pragma unroll
                for (int o = 1; o < 16; o <<= 1) { s1 += __shfl_xor(s1, o); s2 += __shfl_xor(s2, o); }
                if (l15 == 0) {
                    int sl = i * 16 + quad * 4 + r;
                    float mu = s1 * (1.f / 64.f);
                    st_inv[sl] = rsqrtf(fmaxf(s2, 1e-20f));      // 1/||f||; +1e-8 on qn*kn negligible
                    st_var[sl] = (s2 - 64.f * mu * mu) * (1.f / 63.f);  // ddof=1
                    st_mu[sl]  = mu;
                }
            }
    }
    // stage values into per-wave LDS tile: q -> [s][d]; k,v -> [d][s]
    #pragma unroll
    for (int i = 0; i < 4; i++)
        #pragma unroll
        for (int j = 0; j < 4; j++)
            #pragma unroll
            for (int r = 0; r < 4; r++) {
                int sl = i * 16 + quad * 4 + r, d = j * 16 + l15;
                unsigned short bv = f2bf(acc[i][j][r]);
                tile[(typ == 0) ? (sl * 72 + d) : (d * 72 + sl)] = bv;
            }
    // same-wave LDS producer/consumer: compiler inserts lgkmcnt waits

    if (typ == 0) {
        // A2[hb][s][160] = [ q | qhat | var, mu | zeros ]
        unsigned short* ob = A2 + ((size_t)hb * 1024 + sb) * 160;
        #pragma unroll
        for (int it = 0; it < 8; it++) {
            int sl = it * 8 + (lane >> 3), ch = (lane & 7) * 8;
            uint4 raw = *(uint4*)&tile[sl * 72 + ch];
            *(uint4*)(ob + (size_t)sl * 160 + ch) = raw;
            float iv = st_inv[sl];
            uint4 o2;
            o2.x = scale2(raw.x, iv, iv); o2.y = scale2(raw.y, iv, iv);
            o2.z = scale2(raw.z, iv, iv); o2.w = scale2(raw.w, iv, iv);
            *(uint4*)(ob + (size_t)sl * 160 + 64 + ch) = o2;
        }
        {
            int sl = lane;
            uint4 z = {0, 0, 0, 0};
            uint4 t0 = z;
            t0.x = (unsigned)f2bf(st_var[sl]) | ((unsigned)f2bf(st_mu[sl]) << 16);
            unsigned short* p = ob + (size_t)sl * 160 + 128;
            *(uint4*)p = t0;
            *(uint4*)(p + 8) = z; *(uint4*)(p + 16) = z; *(uint4*)(p + 24) = z;
        }
    } else if (typ == 1) {
        // Kt[hb][64][m] raw k (khat applied later in k45 from kinv); stats fp32.
        unsigned short* kb = Kt + (size_t)hb * 64 * 1024 + sb;
        #pragma unroll
        for (int it = 0; it < 8; it++) {
            int d = it * 8 + (lane >> 3), ch = (lane & 7) * 8;
            uint4 raw = *(uint4*)&tile[d * 72 + ch];
            *(uint4*)(kb + (size_t)d * 1024 + ch) = raw;
        }
        int mi = hb * 1024 + sb + lane;
        kinv[mi] = st_inv[lane];
        kvar[mi] = st_var[lane];
        kmu[mi]  = st_mu[lane];
    } else {
        unsigned short* vb = Vt + (size_t)hb * 64 * 1024 + sb;
        #pragma unroll
        for (int it = 0; it < 8; it++) {
            int d = it * 8 + (lane >> 3), ch = (lane & 7) * 8;
            uint4 raw = *(uint4*)&tile[d * 72 + ch];
            *(uint4*)(vb + (size_t)d * 1024 + ch) = raw;
        }
    }
}

// ---------------- K45: per hb full-K: B2t[hb][d][160] = scale(L^T V) --------------
// L rows: [k | k*inv | var | mu | (zeros)]; built in LDS from Kt + stats.
// grid 32, block 256 (4 waves; wave w owns n-cols w*16..+15, 9 m-tiles = 144 rows).
__global__ __launch_bounds__(256) void k45_ktv(
    const unsigned short* __restrict__ Kt, const unsigned short* __restrict__ Vt,
    const float* __restrict__ kinv, const float* __restrict__ kvar,
    const float* __restrict__ kmu, unsigned short* __restrict__ B2t,
    const float* __restrict__ covp, const float* __restrict__ varp)
{
    __shared__ __align__(16) unsigned short As[144][136];
    __shared__ __align__(16) unsigned short Bs[64][136];
    __shared__ float sinv[128], svar[128], smu[128];
    int hb = blockIdx.x;
    int t = threadIdx.x, lane = t & 63, wv = t >> 6;
    int quad = lane >> 4, l15 = lane & 15;
    float cov = covp[0], vw = varp[0];
    float c1 = cov * (1.f / 64.f), cw = 1.f - cov - vw;
    float vw64 = vw * (1.f / 64.f), c2 = -cov;
    const unsigned short* Kb = Kt + (size_t)hb * 64 * 1024;
    const unsigned short* Vb = Vt + (size_t)hb * 64 * 1024;
    int sbase = hb * 1024;
    // zero rows 130-143 (cols 0-127) once so their C-rows stay finite (0)
    if (t < 224) {
        int row = 130 + (t >> 4), co = (t & 15) * 8;
        uint4 z = {0, 0, 0, 0};
        *(uint4*)&As[row][co] = z;
    }
    f32x4 acc[9] = {};
    for (int kc = 0; kc < 8; kc++) {
        __syncthreads();
        if (t < 128) {
            int m = kc * 128 + t;
            sinv[t] = kinv[sbase + m]; svar[t] = kvar[sbase + m]; smu[t] = kmu[sbase + m];
        }
        uint4 kraw[4];
        #pragma unroll
        for (int i = 0; i < 4; i++) {
            int id = i * 256 + t, row = id >> 4, co = (id & 15) * 8;
            kraw[i] = *(const uint4*)(Kb + (size_t)row * 1024 + kc * 128 + co);
            *(uint4*)&As[row][co] = kraw[i];
            uint4 vr = *(const uint4*)(Vb + (size_t)row * 1024 + kc * 128 + co);
            *(uint4*)&Bs[row][co] = vr;
        }
        __syncthreads();
        #pragma unroll
        for (int i = 0; i < 4; i++) {
            int id = i * 256 + t, row = id >> 4, co = (id & 15) * 8;
            float4 iva = *(const float4*)&sinv[co];
            float4 ivb = *(const float4*)&sinv[co + 4];
            uint4 o;
            o.x = scale2(kraw[i].x, iva.x, iva.y); o.y = scale2(kraw[i].y, iva.z, iva.w);
            o.z = scale2(kraw[i].z, ivb.x, ivb.y); o.w = scale2(kraw[i].w, ivb.z, ivb.w);
            *(uint4*)&As[64 + row][co] = o;
        }
        if (t < 32) {
            int which = t >> 4, j0 = (t & 15) * 8;
            const float* sp = (which ? smu : svar) + j0;
            uint4 o;
            o.x = (unsigned)f2bf(sp[0]) | ((unsigned)f2bf(sp[1]) << 16);
            o.y = (unsigned)f2bf(sp[2]) | ((unsigned)f2bf(sp[3]) << 16);
            o.z = (unsigned)f2bf(sp[4]) | ((unsigned)f2bf(sp[5]) << 16);
            o.w = (unsigned)f2bf(sp[6]) | ((unsigned)f2bf(sp[7]) << 16);
            *(uint4*)&As[128 + which][j0] = o;
        }
        __syncthreads();
        #pragma unroll
        for (int kk = 0; kk < 4; kk++) {
            short8 bfrag = *(const short8*)&Bs[wv * 16 + l15][kk * 32 + quad * 8];
            #pragma unroll
            for (int mt = 0; mt < 9; mt++) {
                short8 afrag = *(const short8*)&As[mt * 16 + l15][kk * 32 + quad * 8];
                acc[mt] = __builtin_amdgcn_mfma_f32_16x16x32_bf16(afrag, bfrag, acc[mt], 0, 0, 0);
            }
        }
    }
    unsigned short* ob = B2t + (size_t)hb * 10240;
    int d = wv * 16 + l15;
    #pragma unroll
    for (int mt = 0; mt < 9; mt++)
        #pragma unroll
        for (int r = 0; r < 4; r++) {
            int kk = mt * 16 + quad * 4 + r;
            float scale = (kk < 64) ? c1 : (kk < 128) ? cw : (kk == 128) ? vw64 : (kk == 129) ? c2 : 0.f;
            ob[d * 160 + kk] = f2bf(scale * acc[mt][r]);
        }
}

// ---------------- K6: per (hb) g = A2[1024,160] @ B2 -> g bf16 [4096,512] ---------
__global__ __launch_bounds__(256) void k6_apply(
    const unsigned short* __restrict__ A2, const unsigned short* __restrict__ B2t,
    unsigned short* __restrict__ g)
{
    int hb = blockIdx.y, h = hb >> 2, b = hb & 3;
    int m0 = blockIdx.x * 128;
    int t = threadIdx.x, lane = t & 63, wv = t >> 6;
    int quad = lane >> 4, l15 = lane & 15;
    __shared__ __align__(16) unsigned short As[128][40];
    __shared__ __align__(16) unsigned short Bs[64][40];
    const unsigned short* Ab = A2 + (size_t)hb * 1024 * 160;
    const unsigned short* Bb = B2t + (size_t)hb * 10240;
    f32x4 acc[2][4] = {};
    for (int kt = 0; kt < 160; kt += 32) {
        __syncthreads();
        #pragma unroll
        for (int ld = 0; ld < 2; ld++) {
            int id = ld * 256 + t;
            int row = id >> 2, co = (id & 3) * 8;
            *(uint4*)&As[row][co] = *(const uint4*)(Ab + (size_t)(m0 + row) * 160 + kt + co);
        }
        {
            int row = t >> 2, co = (t & 3) * 8;
            *(uint4*)&Bs[row][co] = *(const uint4*)(Bb + (size_t)row * 160 + kt + co);
        }
        __syncthreads();
        short8 af[2], bf[4];
        #pragma unroll
        for (int i = 0; i < 2; i++) af[i] = *(const short8*)&As[wv * 32 + i * 16 + l15][quad * 8];
        #pragma unroll
        for (int j = 0; j < 4; j++) bf[j] = *(const short8*)&Bs[j * 16 + l15][quad * 8];
        #pragma unroll
        for (int i = 0; i < 2; i++)
            #pragma unroll
            for (int j = 0; j < 4; j++)
                acc[i][j] = __builtin_amdgcn_mfma_f32_16x16x32_bf16(af[i], bf[j], acc[i][j], 0, 0, 0);
    }
    #pragma unroll
    for (int i = 0; i < 2; i++)
        #pragma unroll
        for (int j = 0; j < 4; j++)
            #pragma unroll
            for (int r = 0; r < 4; r++) {
                int rr = m0 + wv * 32 + i * 16 + quad * 4 + r;
                int cc = j * 16 + l15;
                g[((size_t)b * 1024 + rr) * 512 + h * 64 + cc] = f2bf(acc[i][j][r]);
            }
}

// ---------------- gemm_out: C[4096,512](f32) = g @ WoutT^T + bias -----------------
// grid (8, 32): 128x64 tiles, 256 blocks.
__global__ __launch_bounds__(256) void gemm_out(
    const unsigned short* __restrict__ A, const unsigned short* __restrict__ Bt,
    float* __restrict__ C, const float* __restrict__ bias)
{
    __shared__ __align__(16) unsigned short As[128][40];
    __shared__ __align__(16) unsigned short Bs[64][40];
    int t = threadIdx.x, lane = t & 63, wv = t >> 6;
    int quad = lane >> 4, l15 = lane & 15;
    int m0 = blockIdx.y * 128, n0 = blockIdx.x * 64;
    f32x4 acc[2][4] = {};
    for (int kt = 0; kt < 512; kt += 32) {
        __syncthreads();
        #pragma unroll
        for (int ld = 0; ld < 2; ld++) {
            int id = ld * 256 + t;
            int row = id >> 2, co = (id & 3) * 8;
            *(uint4*)&As[row][co] = *(const uint4*)(A + (size_t)(m0 + row) * 512 + kt + co);
        }
        {
            int row = t >> 2, co = (t & 3) * 8;
            *(uint4*)&Bs[row][co] = *(const uint4*)(Bt + (size_t)(n0 + row) * 512 + kt + co);
        }
        __syncthreads();
        short8 af[2], bf[4];
        #pragma unroll
        for (int i = 0; i < 2; i++) af[i] = *(const short8*)&As[wv * 32 + i * 16 + l15][quad * 8];
        #pragma unroll
        for (int j = 0; j < 4; j++) bf[j] = *(const short8*)&Bs[j * 16 + l15][quad * 8];
        #pragma unroll
        for (int i = 0; i < 2; i++)
            #pragma unroll
            for (int j = 0; j < 4; j++)
                acc[i][j] = __builtin_amdgcn_mfma_f32_16x16x32_bf16(af[i], bf[j], acc[i][j], 0, 0, 0);
    }
    #pragma unroll
    for (int i = 0; i < 2; i++)
        #pragma unroll
        for (int j = 0; j < 4; j++)
            #pragma unroll
            for (int r = 0; r < 4; r++) {
                int rr = m0 + wv * 32 + i * 16 + quad * 4 + r;
                int cc = n0 + j * 16 + l15;
                C[(size_t)rr * 512 + cc] = acc[i][j][r] + bias[cc];
            }
}

extern "C" void kernel_launch(void* const* d_in, const int* in_sizes, int n_in,
                              void* d_out, int out_size, void* d_ws, size_t ws_size,
                              hipStream_t stream)
{
    const float* q    = (const float*)d_in[0];
    const float* k    = (const float*)d_in[1];
    const float* v    = (const float*)d_in[2];
    const float* ln_g = (const float*)d_in[3];
    const float* ln_b = (const float*)d_in[4];
    const float* Win  = (const float*)d_in[5];
    const float* Wout = (const float*)d_in[6];
    const float* bout = (const float*)d_in[7];
    const float* covw = (const float*)d_in[8];
    const float* varw = (const float*)d_in[9];

    char* ws = (char*)d_ws;
    size_t off = 0;
    auto alloc = [&](size_t bytes) { size_t r = off; off += (bytes + 255) & ~(size_t)255; return r; };
    unsigned short* xn    = (unsigned short*)(ws + alloc((size_t)3 * R_TOT * DD * 2));
    unsigned short* WinT  = (unsigned short*)(ws + alloc((size_t)DD * DD * 2));
    unsigned short* WoutT = (unsigned short*)(ws + alloc((size_t)DD * DD * 2));
    unsigned short* A2    = (unsigned short*)(ws + alloc((size_t)HB_N * 1024 * 160 * 2));
    unsigned short* Kt    = (unsigned short*)(ws + alloc((size_t)HB_N * 64 * 1024 * 2));
    unsigned short* Vt    = (unsigned short*)(ws + alloc((size_t)HB_N * 64 * 1024 * 2));
    float*          kinv  = (float*)(ws + alloc((size_t)HB_N * 1024 * 4));
    float*          kvar  = (float*)(ws + alloc((size_t)HB_N * 1024 * 4));
    float*          kmu   = (float*)(ws + alloc((size_t)HB_N * 1024 * 4));
    unsigned short* g     = (unsigned short*)(ws + alloc((size_t)R_TOT * DD * 2));
    unsigned short* B2t   = (unsigned short*)(ws + alloc((size_t)HB_N * 10240 * 2));
    (void)ws_size; (void)in_sizes; (void)n_in; (void)out_size;

    k1_ln_prep<<<3072 + 128, 256, 0, stream>>>(q, k, v, ln_g, ln_b, Win, Wout, xn, WinT, WoutT);
    gemm_qkv<<<dim3(4, 96), 256, 0, stream>>>(xn, WinT, A2, Kt, Vt, kinv, kvar, kmu);
    k45_ktv<<<HB_N, 256, 0, stream>>>(Kt, Vt, kinv, kvar, kmu, B2t, covw, varw);
    k6_apply<<<dim3(8, HB_N), 256, 0, stream>>>(A2, B2t, g);
    gemm_out<<<dim3(8, 32), 256, 0, stream>>>(g, WoutT, (float*)d_out, bout);
}